// Round 7
// baseline (206.734 us; speedup 1.0000x reference)
//
#include <hip/hip_runtime.h>
#include <hip/hip_bf16.h>

#define S 4096
#define D 256
#define NB 4
#define XP 272   // padded fp8 row stride (bytes): 256 + 16 -> LDS stride 68 words, 2-way banks

typedef __attribute__((ext_vector_type(8))) __bf16 bf16x8;
typedef __attribute__((ext_vector_type(8))) short s16x8;
typedef __attribute__((ext_vector_type(4))) short s16x4;
typedef __attribute__((ext_vector_type(4))) float f32x4;
typedef __attribute__((ext_vector_type(4))) _Float16 h16x4;

#define MFMA(a, b, c) __builtin_amdgcn_mfma_f32_16x16x32_bf16(a, b, c, 0, 0, 0)
#define MFMA8(a, b, c) __builtin_amdgcn_mfma_f32_16x16x32_fp8_fp8(a, b, c, 0, 0, 0)

__device__ __forceinline__ short f2bf(float f) {
    union { float f; unsigned u; } v; v.f = f;
    unsigned r = v.u + 0x7fffu + ((v.u >> 16) & 1u);   // RNE
    return (short)(r >> 16);
}

__device__ __forceinline__ void g2lds16(const char* g, char* l) {
    __builtin_amdgcn_global_load_lds(
        (const __attribute__((address_space(1))) unsigned int*)g,
        (__attribute__((address_space(3))) unsigned int*)l, 16, 0, 0);
}

// ---------------- prep: x -> fp8 padded rows + row sq-norms; W -> bf16 ----------------
__global__ __launch_bounds__(512) void k_prep(const float* __restrict__ x,
                                              const float* __restrict__ Wv,
                                              unsigned char* __restrict__ xb8,
                                              short* __restrict__ wb,
                                              float* __restrict__ sqg) {
    const int tid = threadIdx.x, w = tid >> 6, lane = tid & 63;
    if (blockIdx.x < 256) {
        const int b = blockIdx.x >> 6, s0 = (blockIdx.x & 63) * 64;
        #pragma unroll
        for (int it = 0; it < 8; it++) {
            int gr = b * S + s0 + it * 8 + w;
            float4 v = ((const float4*)(x + (size_t)gr * D))[lane];
            float ss = v.x * v.x + v.y * v.y + v.z * v.z + v.w * v.w;
            #pragma unroll
            for (int off = 32; off; off >>= 1) ss += __shfl_xor(ss, off, 64);
            int p8 = __builtin_amdgcn_cvt_pk_fp8_f32(v.x, v.y, 0, false);
            p8 = __builtin_amdgcn_cvt_pk_fp8_f32(v.z, v.w, p8, true);
            *(int*)(xb8 + (size_t)gr * XP + lane * 4) = p8;
            if (lane == 0) sqg[gr] = ss;
        }
    } else {
        int idx = ((blockIdx.x - 256) * 512 + tid) * 8;   // 16 blocks cover 65536 W elems
        float4 f0 = *(const float4*)(Wv + idx);
        float4 f1 = *(const float4*)(Wv + idx + 4);
        s16x8 o;
        o[0] = f2bf(f0.x); o[1] = f2bf(f0.y); o[2] = f2bf(f0.z); o[3] = f2bf(f0.w);
        o[4] = f2bf(f1.x); o[5] = f2bf(f1.y); o[6] = f2bf(f1.z); o[7] = f2bf(f1.w);
        *(s16x8*)(wb + idx) = o;
    }
}

// ---------------- V = x @ W^T + b, stored transposed bf16 Vt[b][d][s] ----------------
__global__ __launch_bounds__(512) void k_vproj(const float* __restrict__ x,
                                               const short* __restrict__ wb,
                                               const float* __restrict__ bv,
                                               short* __restrict__ vt) {
    __shared__ short sX[64 * 264];
    __shared__ short sT[256 * 72];

    const int b  = blockIdx.x >> 6;
    const int s0 = (blockIdx.x & 63) * 64;
    const int tid = threadIdx.x;
    const int w = tid >> 6, lane = tid & 63;
    const int col = lane & 15, quad = lane >> 4;

    // W preload (bf16, b128 loads): wave w owns d-strip [w*32, w*32+32)
    bf16x8 wf[2][8];
    #pragma unroll
    for (int ni = 0; ni < 2; ni++)
        #pragma unroll
        for (int ks = 0; ks < 8; ks++)
            wf[ni][ks] = *(const bf16x8*)(wb + (size_t)(w * 32 + ni * 16 + col) * D + ks * 32 + quad * 8);

    // stage x tile (fp32 -> bf16)
    #pragma unroll
    for (int it = 0; it < 8; it++) {
        int row = it * 8 + w;
        float4 v = *(const float4*)(x + (size_t)(b * S + s0 + row) * D + lane * 4);
        s16x4 o;
        o.x = f2bf(v.x); o.y = f2bf(v.y); o.z = f2bf(v.z); o.w = f2bf(v.w);
        *(s16x4*)(sX + row * 264 + lane * 4) = o;
    }
    __syncthreads();

    f32x4 acc[4][2];
    #pragma unroll
    for (int mi = 0; mi < 4; mi++) {
        acc[mi][0] = (f32x4){0.f, 0.f, 0.f, 0.f};
        acc[mi][1] = (f32x4){0.f, 0.f, 0.f, 0.f};
    }
    #pragma unroll
    for (int ks = 0; ks < 8; ks++) {
        bf16x8 a[4];
        #pragma unroll
        for (int mi = 0; mi < 4; mi++)
            a[mi] = *(const bf16x8*)(sX + (mi * 16 + col) * 264 + ks * 32 + quad * 8);
        #pragma unroll
        for (int mi = 0; mi < 4; mi++) {
            acc[mi][0] = MFMA(a[mi], wf[0][ks], acc[mi][0]);
            acc[mi][1] = MFMA(a[mi], wf[1][ks], acc[mi][1]);
        }
    }

    #pragma unroll
    for (int ni = 0; ni < 2; ni++) {
        int d = w * 32 + ni * 16 + col;
        float bvv = bv[d];
        #pragma unroll
        for (int mi = 0; mi < 4; mi++)
            #pragma unroll
            for (int r = 0; r < 4; r++)
                sT[d * 72 + mi * 16 + quad * 4 + r] = f2bf(acc[mi][ni][r] + bvv);
    }
    __syncthreads();
    {
        int d = tid >> 1, half = (tid & 1) * 32;
        short* dst = vt + (size_t)(b * D + d) * S + s0 + half;
        const short* src = sT + d * 72 + half;
        #pragma unroll
        for (int i = 0; i < 4; i++)
            *(s16x8*)(dst + i * 8) = *(const s16x8*)(src + i * 8);
    }
}

// ---------------- Main fused attention ----------------
// 256 threads = 4 waves; q-tile 64, t-tile 32; fp8 gram (padded stride-272 LDS image:
// affine ds_read offsets + 2-way-free banks), bf16 PV; one barrier/iter.
template <int TSPLIT>
__global__ __launch_bounds__(256) void k_attn(const unsigned char* __restrict__ xb8,
                                              const short* __restrict__ vt,
                                              const float* __restrict__ sq,
                                              const float* __restrict__ logt,
                                              float* __restrict__ outp,
                                              _Float16* __restrict__ pex,
                                              float* __restrict__ rws) {
    __shared__ char sXt[2][32 * XP];     // 8704 B each, stride 272
    __shared__ short sK[2][64 * 36];
    __shared__ float sRow[64];

    const int tid = threadIdx.x;
    const int w = tid >> 6, lane = tid & 63;
    const int col = lane & 15, quad = lane >> 4;

    int b, th, qt;
    if (TSPLIT == 4) {
        b  = (blockIdx.x >> 1) & 3;
        th = (blockIdx.x & 1) | (((blockIdx.x >> 3) & 1) << 1);
        qt = blockIdx.x >> 4;
    } else {
        b = blockIdx.x & 3;
        th = 0;
        qt = blockIdx.x >> 2;
    }
    const int q0 = qt * 64;
    const int t_base = th * (S / TSPLIT);
    const int NT = (S / TSPLIT) / 32;

    float temp = fmaxf(__expf(logt[0]), 1e-5f);
    float t2 = temp * temp;

    const unsigned char* xtb = xb8 + (size_t)b * S * XP;
    const short* vtb = vt + (size_t)b * D * S;
    const float* sqb = sq + b * S;

    long xq[8];
    {
        const unsigned char* xrow = xtb + (size_t)(q0 + w * 16 + col) * XP + quad * 8;
        #pragma unroll
        for (int ks = 0; ks < 8; ks++)
            xq[ks] = *(const long*)(xrow + ks * 32);
    }
    float sqq[4];
    #pragma unroll
    for (int rr = 0; rr < 4; rr++)
        sqq[rr] = sqb[q0 + w * 16 + quad * 4 + rr];

    f32x4 acc[4][4];
    #pragma unroll
    for (int mi = 0; mi < 4; mi++)
        #pragma unroll
        for (int ni = 0; ni < 4; ni++)
            acc[mi][ni] = (f32x4){0.f, 0.f, 0.f, 0.f};
    float rs[4] = {0.f, 0.f, 0.f, 0.f};

    {   // prologue: stage tile 0 (544 16B chunks)
        const char* g = (const char*)(xtb + (size_t)t_base * XP);
        g2lds16(g + tid * 16, &sXt[0][tid * 16]);
        g2lds16(g + (tid + 256) * 16, &sXt[0][(tid + 256) * 16]);
        if (tid < 32) g2lds16(g + (tid + 512) * 16, &sXt[0][(tid + 512) * 16]);
    }

    for (int i = 0; i < NT; i++) {
        const int t0 = t_base + i * 32;
        const int cur = i & 1;
        __syncthreads();

        if (i + 1 < NT) {
            const char* g = (const char*)(xtb + (size_t)(t0 + 32) * XP);
            char* l = sXt[cur ^ 1];
            g2lds16(g + tid * 16, l + tid * 16);
            g2lds16(g + (tid + 256) * 16, l + (tid + 256) * 16);
            if (tid < 32) g2lds16(g + (tid + 512) * 16, l + (tid + 512) * 16);
        }

        bf16x8 vb[4];
        if (i > 0) {
            const int tp = t0 - 32;
            #pragma unroll
            for (int ni = 0; ni < 4; ni++)
                vb[ni] = *(const bf16x8*)(vtb + (size_t)(w * 64 + ni * 16 + col) * S + tp + quad * 8);
        }
        float sqt0 = sqb[t0 + col], sqt1 = sqb[t0 + 16 + col];

        // ---- gram (fp8): P[16 q][32 t]; affine LDS offsets ----
        f32x4 p2v[2];
        p2v[0] = (f32x4){0.f, 0.f, 0.f, 0.f};
        p2v[1] = (f32x4){0.f, 0.f, 0.f, 0.f};
        {
            const char* base = &sXt[cur][col * XP + quad * 8];
            #pragma unroll
            for (int ks = 0; ks < 8; ks++) {
                long b0 = *(const long*)(base + ks * 32);
                long b1 = *(const long*)(base + 16 * XP + ks * 32);
                p2v[0] = MFMA8(xq[ks], b0, p2v[0]);
                p2v[1] = MFMA8(xq[ks], b1, p2v[1]);
            }
        }

        // ---- Cauchy transform + rowsum + sK write ----
        #pragma unroll
        for (int t_ = 0; t_ < 2; t_++) {
            float sqt = t_ ? sqt1 : sqt0;
            int tg = t0 + t_ * 16 + col;
            #pragma unroll
            for (int rr = 0; rr < 4; rr++) {
                float d2 = fmaxf(sqq[rr] + sqt - 2.f * p2v[t_][rr], 0.f);
                float kv = t2 * __builtin_amdgcn_rcpf(t2 + d2);
                if (q0 + w * 16 + quad * 4 + rr == tg) kv = 1.f;   // exact diagonal
                rs[rr] += kv;
                sK[cur][(w * 16 + quad * 4 + rr) * 36 + t_ * 16 + col] = f2bf(kv);
            }
        }

        // ---- PV_{i-1} (bf16) ----
        if (i > 0) {
            #pragma unroll
            for (int mi = 0; mi < 4; mi++) {
                bf16x8 af = *(const bf16x8*)(&sK[cur ^ 1][(mi * 16 + col) * 36 + quad * 8]);
                #pragma unroll
                for (int ni = 0; ni < 4; ni++)
                    acc[mi][ni] = MFMA(af, vb[ni], acc[mi][ni]);
            }
        }
    }

    __syncthreads();
    {   // final PV
        const int tp = t_base + (NT - 1) * 32;
        const int cur = (NT - 1) & 1;
        bf16x8 vb[4];
        #pragma unroll
        for (int ni = 0; ni < 4; ni++)
            vb[ni] = *(const bf16x8*)(vtb + (size_t)(w * 64 + ni * 16 + col) * S + tp + quad * 8);
        #pragma unroll
        for (int mi = 0; mi < 4; mi++) {
            bf16x8 af = *(const bf16x8*)(&sK[cur][(mi * 16 + col) * 36 + quad * 8]);
            #pragma unroll
            for (int ni = 0; ni < 4; ni++)
                acc[mi][ni] = MFMA(af, vb[ni], acc[mi][ni]);
        }
    }

    #pragma unroll
    for (int rr = 0; rr < 4; rr++) {
        float v = rs[rr];
        v += __shfl_xor(v, 1, 64);
        v += __shfl_xor(v, 2, 64);
        v += __shfl_xor(v, 4, 64);
        v += __shfl_xor(v, 8, 64);
        if (col == 0) sRow[w * 16 + quad * 4 + rr] = v;
    }
    __syncthreads();

    if (TSPLIT == 1) {
        float* ob = outp + (size_t)(b * S + q0) * D;
        #pragma unroll
        for (int mi = 0; mi < 4; mi++)
            #pragma unroll
            for (int rr = 0; rr < 4; rr++) {
                float rinv = __builtin_amdgcn_rcpf(fmaxf(sRow[mi * 16 + quad * 4 + rr], 1e-8f));
                #pragma unroll
                for (int ni = 0; ni < 4; ni++)
                    ob[(size_t)(mi * 16 + quad * 4 + rr) * D + w * 64 + ni * 16 + col] =
                        acc[mi][ni][rr] * rinv;
            }
    } else {
        if (tid < 64) rws[(size_t)th * NB * S + b * S + q0 + tid] = sRow[tid];
        _Float16* ob = pex + (size_t)th * NB * S * D + (size_t)(b * S + q0) * D;
        #pragma unroll
        for (int mi = 0; mi < 4; mi++)
            #pragma unroll
            for (int rr = 0; rr < 4; rr++)
                #pragma unroll
                for (int ni = 0; ni < 4; ni++)
                    ob[(size_t)(mi * 16 + quad * 4 + rr) * D + w * 64 + ni * 16 + col] =
                        (_Float16)acc[mi][ni][rr];
    }
}

// ---------------- combine: out = sum(fp16 partials) / max(sum(rowsums), eps) ----------------
template <int TSPLIT>
__global__ __launch_bounds__(256) void k_combine(float* __restrict__ outp,
                                                 const _Float16* __restrict__ pex,
                                                 const float* __restrict__ rws) {
    int i4 = blockIdx.x * 256 + threadIdx.x;
    int gs = i4 >> 6;
    float sum = rws[gs];
    #pragma unroll
    for (int p = 1; p < TSPLIT; p++) sum += rws[(size_t)p * NB * S + gs];
    float rinv = __builtin_amdgcn_rcpf(fmaxf(sum, 1e-8f));
    float4 o = {0.f, 0.f, 0.f, 0.f};
    #pragma unroll
    for (int p = 0; p < TSPLIT; p++) {
        h16x4 e = *(const h16x4*)(pex + (size_t)p * NB * S * D + (size_t)i4 * 4);
        o.x += (float)e[0]; o.y += (float)e[1]; o.z += (float)e[2]; o.w += (float)e[3];
    }
    o.x *= rinv; o.y *= rinv; o.z *= rinv; o.w *= rinv;
    ((float4*)outp)[i4] = o;
}

extern "C" void kernel_launch(void* const* d_in, const int* in_sizes, int n_in,
                              void* d_out, int out_size, void* d_ws, size_t ws_size,
                              hipStream_t stream) {
    const float* x    = (const float*)d_in[0];
    const float* Wv   = (const float*)d_in[1];
    const float* bv   = (const float*)d_in[2];
    const float* logt = (const float*)d_in[3];
    float* out = (float*)d_out;

    char* ws = (char*)d_ws;
    unsigned char* xb8 = (unsigned char*)ws;          // fp8 x padded [B][S][272]  4.46 MB
    short* wb  = (short*)(ws + 4456448);              // bf16 W                    128 KB
    short* vt  = (short*)(ws + 4587520);              // bf16 V^T [B][D][S]        8 MB
    float* sq  = (float*)(ws + 12976128);             // ||x||^2 [B][S]            64 KB
    float* rws = (float*)(ws + 13041664);             // rowsums [T][B][S]         256 KB
    _Float16* pex = (_Float16*)(ws + 13303808);       // fp16 partials [T][B][S][D]
    const size_t PH = (size_t)NB * S * D * 2u;        // 8.39 MB per fp16 partial

    k_prep<<<272, 512, 0, stream>>>(x, Wv, xb8, wb, sq);
    k_vproj<<<NB * (S / 64), 512, 0, stream>>>(x, wb, bv, vt);

    if (ws_size >= 13303808u + 4u * PH) {
        k_attn<4><<<NB * (S / 64) * 4, 256, 0, stream>>>(xb8, vt, sq, logt, out, pex, rws);
        k_combine<4><<<(NB * S * D / 4) / 256, 256, 0, stream>>>(out, pex, rws);
    } else {
        k_attn<1><<<NB * (S / 64), 256, 0, stream>>>(xb8, vt, sq, logt, out, nullptr, nullptr);
    }
}

// Round 8
// 196.523 us; speedup vs baseline: 1.0520x; 1.0520x over previous
//
#include <hip/hip_runtime.h>
#include <hip/hip_bf16.h>

#define S 4096
#define D 256
#define NB 4

typedef __attribute__((ext_vector_type(8))) __bf16 bf16x8;
typedef __attribute__((ext_vector_type(8))) short s16x8;
typedef __attribute__((ext_vector_type(4))) short s16x4;
typedef __attribute__((ext_vector_type(4))) float f32x4;

#define MFMA(a, b, c) __builtin_amdgcn_mfma_f32_16x16x32_bf16(a, b, c, 0, 0, 0)
#define MFMA8(a, b, c) __builtin_amdgcn_mfma_f32_16x16x32_fp8_fp8(a, b, c, 0, 0, 0)

__device__ __forceinline__ short f2bf(float f) {
    union { float f; unsigned u; } v; v.f = f;
    unsigned r = v.u + 0x7fffu + ((v.u >> 16) & 1u);   // RNE
    return (short)(r >> 16);
}

__device__ __forceinline__ void g2lds16(const char* g, char* l) {
    __builtin_amdgcn_global_load_lds(
        (const __attribute__((address_space(1))) unsigned int*)g,
        (__attribute__((address_space(3))) unsigned int*)l, 16, 0, 0);
}

// ---------------- fused: x->fp8(XOR-swizzled)+bf16, sq-norms, V = xW^T+b transposed ----------------
// 32 s-rows per block, grid 512 -> 2 blocks/CU (R6's version was 64-row/grid-256 = 1 block/CU,
// latency-bound). Reads x ONCE (R7's split read it twice). xb8 format identical to R6:
// 256B rows, 16B chunk c stored at c ^ (row&7).
__global__ __launch_bounds__(512) void k_vprojx(const float* __restrict__ x,
                                                const float* __restrict__ Wv,
                                                const float* __restrict__ bv,
                                                unsigned char* __restrict__ xb8,
                                                float* __restrict__ sqg,
                                                short* __restrict__ vt) {
    __shared__ short sX[32 * 264];   // 16.9 KB
    __shared__ short sT[256 * 40];   // 20.0 KB

    const int b  = blockIdx.x >> 7;
    const int s0 = (blockIdx.x & 127) * 32;
    const int tid = threadIdx.x;
    const int w = tid >> 6, lane = tid & 63;
    const int col = lane & 15, quad = lane >> 4;

    // ---- stage x: row = tid>>4, 16 threads per row; convert to bf16(LDS) + fp8(global) ----
    {
        const int row = tid >> 4, c16 = tid & 15;
        const float* src = x + (size_t)(b * S + s0 + row) * D + c16 * 16;
        float ss = 0.f;
        int p8[4];
        #pragma unroll
        for (int j = 0; j < 4; j++) {
            float4 v = ((const float4*)src)[j];
            ss += v.x * v.x + v.y * v.y + v.z * v.z + v.w * v.w;
            s16x4 o;
            o.x = f2bf(v.x); o.y = f2bf(v.y); o.z = f2bf(v.z); o.w = f2bf(v.w);
            *(s16x4*)(sX + row * 264 + c16 * 16 + j * 4) = o;
            int pk = __builtin_amdgcn_cvt_pk_fp8_f32(v.x, v.y, 0, false);
            p8[j] = __builtin_amdgcn_cvt_pk_fp8_f32(v.z, v.w, pk, true);
        }
        ss += __shfl_xor(ss, 1, 64);
        ss += __shfl_xor(ss, 2, 64);
        ss += __shfl_xor(ss, 4, 64);
        ss += __shfl_xor(ss, 8, 64);
        *(int4*)(xb8 + (size_t)(b * S + s0 + row) * D + ((c16 ^ (row & 7)) << 4)) =
            *(int4*)p8;
        if (c16 == 0) sqg[b * S + s0 + row] = ss;
    }

    // ---- W preload (fp32->bf16 regs): wave w owns d-strip [w*32, w*32+32) ----
    bf16x8 wf[2][8];
    #pragma unroll
    for (int ni = 0; ni < 2; ni++)
        #pragma unroll
        for (int ks = 0; ks < 8; ks++) {
            const float* p = Wv + (size_t)(w * 32 + ni * 16 + col) * D + ks * 32 + quad * 8;
            float4 f0 = *(const float4*)p;
            float4 f1 = *(const float4*)(p + 4);
            s16x8 o;
            o[0] = f2bf(f0.x); o[1] = f2bf(f0.y); o[2] = f2bf(f0.z); o[3] = f2bf(f0.w);
            o[4] = f2bf(f1.x); o[5] = f2bf(f1.y); o[6] = f2bf(f1.z); o[7] = f2bf(f1.w);
            wf[ni][ks] = *(bf16x8*)&o;
        }
    __syncthreads();

    // ---- gemm: 32 s-rows x 32 d-cols per wave ----
    f32x4 acc[2][2];
    #pragma unroll
    for (int mi = 0; mi < 2; mi++) {
        acc[mi][0] = (f32x4){0.f, 0.f, 0.f, 0.f};
        acc[mi][1] = (f32x4){0.f, 0.f, 0.f, 0.f};
    }
    #pragma unroll
    for (int ks = 0; ks < 8; ks++) {
        bf16x8 a[2];
        #pragma unroll
        for (int mi = 0; mi < 2; mi++)
            a[mi] = *(const bf16x8*)(sX + (mi * 16 + col) * 264 + ks * 32 + quad * 8);
        #pragma unroll
        for (int mi = 0; mi < 2; mi++) {
            acc[mi][0] = MFMA(a[mi], wf[0][ks], acc[mi][0]);
            acc[mi][1] = MFMA(a[mi], wf[1][ks], acc[mi][1]);
        }
    }

    // ---- bias + transpose-stage + coalesced Vt write ----
    #pragma unroll
    for (int ni = 0; ni < 2; ni++) {
        int d = w * 32 + ni * 16 + col;
        float bvv = bv[d];
        #pragma unroll
        for (int mi = 0; mi < 2; mi++)
            #pragma unroll
            for (int r = 0; r < 4; r++)
                sT[d * 40 + mi * 16 + quad * 4 + r] = f2bf(acc[mi][ni][r] + bvv);
    }
    __syncthreads();
    {
        int d = tid >> 1, half = (tid & 1) * 16;
        short* dst = vt + (size_t)(b * D + d) * S + s0 + half;
        const short* src = sT + d * 40 + half;
        *(s16x8*)(dst) = *(const s16x8*)(src);
        *(s16x8*)(dst + 8) = *(const s16x8*)(src + 8);
    }
}

// ---------------- Main fused attention (R6 version, byte-for-byte) ----------------
// 256 threads = 4 waves. q-tile 64, t-tile 32. Gram in fp8 (A=regs, B=LDS b64 reads),
// PV in bf16 (A=sK LDS, B=Vt global->reg). One __syncthreads per iter.
template <int TSPLIT>
__global__ __launch_bounds__(256) void k_attn(const unsigned char* __restrict__ xb8,
                                              const short* __restrict__ vt,
                                              const float* __restrict__ sq,
                                              const float* __restrict__ logt,
                                              float* __restrict__ outp,
                                              float* __restrict__ pex,
                                              float* __restrict__ rws) {
    __shared__ char sXt[2][32 * 256];    // fp8 tile image (xb8 pre-swizzled), 8 KB each
    __shared__ short sK[2][64 * 36];     // kernel tile [q][t] bf16, stride 36
    __shared__ float sRow[64];

    const int tid = threadIdx.x;
    const int w = tid >> 6, lane = tid & 63;
    const int col = lane & 15, quad = lane >> 4;
    const int cx = col & 7;

    int b, th, qt;
    if (TSPLIT == 4) {
        b  = (blockIdx.x >> 1) & 3;
        th = (blockIdx.x & 1) | (((blockIdx.x >> 3) & 1) << 1);
        qt = blockIdx.x >> 4;
    } else if (TSPLIT == 2) {
        b  = (blockIdx.x & 7) >> 1;
        th = blockIdx.x & 1;
        qt = blockIdx.x >> 3;
    } else {
        b = blockIdx.x & 3;
        th = 0;
        qt = blockIdx.x >> 2;
    }
    const int q0 = qt * 64;
    const int t_base = th * (S / TSPLIT);
    const int NT = (S / TSPLIT) / 32;

    float temp = fmaxf(__expf(logt[0]), 1e-5f);
    float t2 = temp * temp;

    const unsigned char* xtb = xb8 + (size_t)b * S * D;
    const short* vtb = vt + (size_t)b * D * S;
    const float* sqb = sq + b * S;

    // gram A-frags (fp8): q-row q0 + w*16 + col, 8 bytes per k-step (swizzle-aware)
    long xq[8];
    {
        const unsigned char* xrow = xtb + (size_t)(q0 + w * 16 + col) * D;
        #pragma unroll
        for (int ks = 0; ks < 8; ks++)
            xq[ks] = *(const long*)(xrow + (((ks * 2 + (quad >> 1)) ^ cx) << 4) + (quad & 1) * 8);
    }
    float sqq[4];
    #pragma unroll
    for (int rr = 0; rr < 4; rr++)
        sqq[rr] = sqb[q0 + w * 16 + quad * 4 + rr];

    f32x4 acc[4][4];
    #pragma unroll
    for (int mi = 0; mi < 4; mi++)
        #pragma unroll
        for (int ni = 0; ni < 4; ni++)
            acc[mi][ni] = (f32x4){0.f, 0.f, 0.f, 0.f};
    float rs[4] = {0.f, 0.f, 0.f, 0.f};

    // prologue: async-stage tile 0 (8 KB: 2 chunks/thread)
    {
        const char* g = (const char*)(xtb + (size_t)t_base * D);
        #pragma unroll
        for (int p = 0; p < 2; p++) {
            int c = p * 256 + tid;
            g2lds16(g + c * 16, &sXt[0][c * 16]);
        }
    }

    for (int i = 0; i < NT; i++) {
        const int t0 = t_base + i * 32;
        const int cur = i & 1;
        __syncthreads();   // staging(i) landed + sK[(i-1)&1] written; PV_{i-2} reads done

        if (i + 1 < NT) {   // async-stage tile i+1
            const char* g = (const char*)(xtb + (size_t)(t0 + 32) * D);
            #pragma unroll
            for (int p = 0; p < 2; p++) {
                int c = p * 256 + tid;
                g2lds16(g + c * 16, &sXt[cur ^ 1][c * 16]);
            }
        }

        // Vt for PV_{i-1} (issue early, consume at end)
        bf16x8 vb[4];
        if (i > 0) {
            const int tp = t0 - 32;
            #pragma unroll
            for (int ni = 0; ni < 4; ni++)
                vb[ni] = *(const bf16x8*)(vtb + (size_t)(w * 64 + ni * 16 + col) * S + tp + quad * 8);
        }
        float sqt0 = sqb[t0 + col], sqt1 = sqb[t0 + 16 + col];

        // ---- gram (fp8): P[16 q][32 t] ----
        f32x4 p2v[2];
        p2v[0] = (f32x4){0.f, 0.f, 0.f, 0.f};
        p2v[1] = (f32x4){0.f, 0.f, 0.f, 0.f};
        #pragma unroll
        for (int ks = 0; ks < 8; ks++) {
            int co = (((ks * 2 + (quad >> 1)) ^ cx) << 4) + (quad & 1) * 8;
            long b0 = *(const long*)(&sXt[cur][col * 256 + co]);
            long b1 = *(const long*)(&sXt[cur][(col + 16) * 256 + co]);
            p2v[0] = MFMA8(xq[ks], b0, p2v[0]);
            p2v[1] = MFMA8(xq[ks], b1, p2v[1]);
        }

        // ---- Cauchy transform + rowsum + sK[cur] write ----
        #pragma unroll
        for (int t_ = 0; t_ < 2; t_++) {
            float sqt = t_ ? sqt1 : sqt0;
            int tg = t0 + t_ * 16 + col;
            #pragma unroll
            for (int rr = 0; rr < 4; rr++) {
                float d2 = fmaxf(sqq[rr] + sqt - 2.f * p2v[t_][rr], 0.f);
                float kv = t2 * __builtin_amdgcn_rcpf(t2 + d2);
                if (q0 + w * 16 + quad * 4 + rr == tg) kv = 1.f;   // exact diagonal
                rs[rr] += kv;
                sK[cur][(w * 16 + quad * 4 + rr) * 36 + t_ * 16 + col] = f2bf(kv);
            }
        }

        // ---- PV_{i-1} (bf16): acc[64 q][64 d-strip] += K_{i-1} @ V^T ----
        if (i > 0) {
            #pragma unroll
            for (int mi = 0; mi < 4; mi++) {
                bf16x8 af = *(const bf16x8*)(&sK[cur ^ 1][(mi * 16 + col) * 36 + quad * 8]);
                #pragma unroll
                for (int ni = 0; ni < 4; ni++)
                    acc[mi][ni] = MFMA(af, vb[ni], acc[mi][ni]);
            }
        }
    }

    // ---- epilogue: final PV ----
    __syncthreads();
    {
        const int tp = t_base + (NT - 1) * 32;
        const int cur = (NT - 1) & 1;
        bf16x8 vb[4];
        #pragma unroll
        for (int ni = 0; ni < 4; ni++)
            vb[ni] = *(const bf16x8*)(vtb + (size_t)(w * 64 + ni * 16 + col) * S + tp + quad * 8);
        #pragma unroll
        for (int mi = 0; mi < 4; mi++) {
            bf16x8 af = *(const bf16x8*)(&sK[cur][(mi * 16 + col) * 36 + quad * 8]);
            #pragma unroll
            for (int ni = 0; ni < 4; ni++)
                acc[mi][ni] = MFMA(af, vb[ni], acc[mi][ni]);
        }
    }

    // rowsum: reduce over 16 t-cols in wave; unique writer per q-row
    #pragma unroll
    for (int rr = 0; rr < 4; rr++) {
        float v = rs[rr];
        v += __shfl_xor(v, 1, 64);
        v += __shfl_xor(v, 2, 64);
        v += __shfl_xor(v, 4, 64);
        v += __shfl_xor(v, 8, 64);
        if (col == 0) sRow[w * 16 + quad * 4 + rr] = v;
    }
    __syncthreads();

    if (TSPLIT == 1) {
        float* ob = outp + (size_t)(b * S + q0) * D;
        #pragma unroll
        for (int mi = 0; mi < 4; mi++)
            #pragma unroll
            for (int rr = 0; rr < 4; rr++) {
                float rinv = __builtin_amdgcn_rcpf(fmaxf(sRow[mi * 16 + quad * 4 + rr], 1e-8f));
                #pragma unroll
                for (int ni = 0; ni < 4; ni++)
                    ob[(size_t)(mi * 16 + quad * 4 + rr) * D + w * 64 + ni * 16 + col] =
                        acc[mi][ni][rr] * rinv;
            }
    } else {
        if (tid < 64) rws[(size_t)th * NB * S + b * S + q0 + tid] = sRow[tid];
        float* ob = (th == 0 ? outp : pex + (size_t)(th - 1) * NB * S * D) + (size_t)(b * S + q0) * D;
        #pragma unroll
        for (int mi = 0; mi < 4; mi++)
            #pragma unroll
            for (int rr = 0; rr < 4; rr++)
                #pragma unroll
                for (int ni = 0; ni < 4; ni++)
                    ob[(size_t)(mi * 16 + quad * 4 + rr) * D + w * 64 + ni * 16 + col] =
                        acc[mi][ni][rr];
    }
}

// ---------------- combine: out = sum(partials) / max(sum(rowsums), eps) ----------------
template <int TSPLIT>
__global__ __launch_bounds__(256) void k_combine(float* __restrict__ outp,
                                                 const float* __restrict__ pex,
                                                 const float* __restrict__ rws) {
    int i4 = blockIdx.x * 256 + threadIdx.x;
    int gs = i4 >> 6;   // D/4 = 64 float4 per row
    float sum = rws[gs];
    #pragma unroll
    for (int p = 1; p < TSPLIT; p++) sum += rws[(size_t)p * NB * S + gs];
    float rinv = __builtin_amdgcn_rcpf(fmaxf(sum, 1e-8f));
    float4 o = ((const float4*)outp)[i4];
    #pragma unroll
    for (int p = 1; p < TSPLIT; p++) {
        float4 e = ((const float4*)(pex + (size_t)(p - 1) * NB * S * D))[i4];
        o.x += e.x; o.y += e.y; o.z += e.z; o.w += e.w;
    }
    o.x *= rinv; o.y *= rinv; o.z *= rinv; o.w *= rinv;
    ((float4*)outp)[i4] = o;
}

extern "C" void kernel_launch(void* const* d_in, const int* in_sizes, int n_in,
                              void* d_out, int out_size, void* d_ws, size_t ws_size,
                              hipStream_t stream) {
    const float* x    = (const float*)d_in[0];
    const float* Wv   = (const float*)d_in[1];
    const float* bv   = (const float*)d_in[2];
    const float* logt = (const float*)d_in[3];
    float* out = (float*)d_out;

    char* ws = (char*)d_ws;
    unsigned char* xb8 = (unsigned char*)ws;          // fp8 x (swizzled) [B][S][D]  4 MB
    short* vt  = (short*)(ws + 4194304);              // bf16 V^T [B][D][S]          8 MB
    float* sq  = (float*)(ws + 12582912);             // ||x||^2  [B][S]             64 KB
    float* rws = (float*)(ws + 12648448);             // rowsums  [T][B][S]          256 KB
    const size_t pex_off = 12910592u;
    const size_t P = (size_t)NB * S * D * 4u;         // 16.78 MB per fp32 partial

    k_vprojx<<<NB * (S / 32), 512, 0, stream>>>(x, Wv, bv, xb8, sq, vt);

    const size_t need4 = pex_off + 3u * P;
    const size_t need2 = pex_off + 1u * P;
    if (ws_size >= need4) {
        float* pex = (float*)(ws + pex_off);
        k_attn<4><<<NB * (S / 64) * 4, 256, 0, stream>>>(xb8, vt, sq, logt, out, pex, rws);
        k_combine<4><<<(NB * S * D / 4) / 256, 256, 0, stream>>>(out, pex, rws);
    } else if (ws_size >= need2) {
        float* pex = (float*)(ws + pex_off);
        k_attn<2><<<NB * (S / 64) * 2, 256, 0, stream>>>(xb8, vt, sq, logt, out, pex, rws);
        k_combine<2><<<(NB * S * D / 4) / 256, 256, 0, stream>>>(out, pex, rws);
    } else {
        k_attn<1><<<NB * (S / 64), 256, 0, stream>>>(xb8, vt, sq, logt, out, nullptr, nullptr);
    }
}

// Round 9
// 176.981 us; speedup vs baseline: 1.1681x; 1.1104x over previous
//
#include <hip/hip_runtime.h>
#include <hip/hip_bf16.h>

#define S 4096
#define D 256
#define NB 4

typedef __attribute__((ext_vector_type(8))) __bf16 bf16x8;
typedef __attribute__((ext_vector_type(8))) short s16x8;
typedef __attribute__((ext_vector_type(4))) short s16x4;
typedef __attribute__((ext_vector_type(4))) float f32x4;
typedef __attribute__((ext_vector_type(8))) _Float16 h16x8;

#define MFMA(a, b, c) __builtin_amdgcn_mfma_f32_16x16x32_bf16(a, b, c, 0, 0, 0)
#define MFMA8(a, b, c) __builtin_amdgcn_mfma_f32_16x16x32_fp8_fp8(a, b, c, 0, 0, 0)

__device__ __forceinline__ short f2bf(float f) {
    union { float f; unsigned u; } v; v.f = f;
    unsigned r = v.u + 0x7fffu + ((v.u >> 16) & 1u);   // RNE
    return (short)(r >> 16);
}

__device__ __forceinline__ void g2lds16(const char* g, char* l) {
    __builtin_amdgcn_global_load_lds(
        (const __attribute__((address_space(1))) unsigned int*)g,
        (__attribute__((address_space(3))) unsigned int*)l, 16, 0, 0);
}

// ---------------- prep: x -> fp8(XOR-swizzled) + bf16 x^T + row norms; W -> bf16 ----------------
// Pure streaming (no GEMM): blocks 0..511 transpose 32 s-rows each; blocks 512..527 convert W.
__global__ __launch_bounds__(256) void k_prep(const float* __restrict__ x,
                                              const float* __restrict__ Wv,
                                              unsigned char* __restrict__ xb8,
                                              short* __restrict__ xt,
                                              short* __restrict__ wb,
                                              float* __restrict__ sqg) {
    const int tid = threadIdx.x;
    if (blockIdx.x >= 512) {   // W fp32 -> bf16
        int idx = (((int)blockIdx.x - 512) * 256 + tid) * 16;
        #pragma unroll
        for (int h = 0; h < 2; h++) {
            float4 f0 = *(const float4*)(Wv + idx + h * 8);
            float4 f1 = *(const float4*)(Wv + idx + h * 8 + 4);
            s16x8 o;
            o[0] = f2bf(f0.x); o[1] = f2bf(f0.y); o[2] = f2bf(f0.z); o[3] = f2bf(f0.w);
            o[4] = f2bf(f1.x); o[5] = f2bf(f1.y); o[6] = f2bf(f1.z); o[7] = f2bf(f1.w);
            *(s16x8*)(wb + idx + h * 8) = o;
        }
        return;
    }

    __shared__ short sX[32 * 264];
    const int b = blockIdx.x >> 7, s0 = (blockIdx.x & 127) * 32;
    const int row = tid >> 3, c8 = tid & 7;
    {
        const float* src = x + (size_t)(b * S + s0 + row) * D + c8 * 32;
        unsigned char* xrow = xb8 + (size_t)(b * S + s0 + row) * D;
        float ss = 0.f;
        int p8[8];
        #pragma unroll
        for (int j = 0; j < 8; j++) {
            float4 v = ((const float4*)src)[j];
            ss += v.x * v.x + v.y * v.y + v.z * v.z + v.w * v.w;
            s16x4 o;
            o.x = f2bf(v.x); o.y = f2bf(v.y); o.z = f2bf(v.z); o.w = f2bf(v.w);
            *(s16x4*)(sX + row * 264 + c8 * 32 + j * 4) = o;
            int pk = __builtin_amdgcn_cvt_pk_fp8_f32(v.x, v.y, 0, false);
            p8[j] = __builtin_amdgcn_cvt_pk_fp8_f32(v.z, v.w, pk, true);
        }
        ss += __shfl_xor(ss, 1, 64);
        ss += __shfl_xor(ss, 2, 64);
        ss += __shfl_xor(ss, 4, 64);
        int4 lo = {p8[0], p8[1], p8[2], p8[3]};
        int4 hi = {p8[4], p8[5], p8[6], p8[7]};
        *(int4*)(xrow + (((2 * c8) ^ (row & 7)) << 4)) = lo;
        *(int4*)(xrow + (((2 * c8 + 1) ^ (row & 7)) << 4)) = hi;
        if (c8 == 0) sqg[b * S + s0 + row] = ss;
    }
    __syncthreads();
    {   // transposed write: thread owns d = tid, gathers 32 s-values (2-way banks = free)
        short tmp[32];
        #pragma unroll
        for (int s = 0; s < 32; s++) tmp[s] = sX[s * 264 + tid];
        short* dst = xt + (size_t)(b * D + tid) * S + s0;
        #pragma unroll
        for (int i = 0; i < 4; i++)
            *(s16x8*)(dst + i * 8) = *(const s16x8*)(tmp + i * 8);
    }
}

// ---------------- Main fused attention (R8 structure; un-scaled kernel u = 1/(t2+d2)) ----------------
// 256 threads = 4 waves. q-tile 64, t-tile 32. Gram fp8 (A=regs, B=LDS), PV bf16 vs x^T.
// Writes UNNORMALIZED Y = K@x (fp16) + rowsums; k_post normalizes and applies W^T+b.
template <int TSPLIT>
__global__ __launch_bounds__(256) void k_attn(const unsigned char* __restrict__ xb8,
                                              const short* __restrict__ xt,
                                              const float* __restrict__ sq,
                                              const float* __restrict__ logt,
                                              _Float16* __restrict__ pex,
                                              float* __restrict__ rws) {
    __shared__ char sXt[2][32 * 256];
    __shared__ short sK[2][64 * 36];
    __shared__ float sRow[64];

    const int tid = threadIdx.x;
    const int w = tid >> 6, lane = tid & 63;
    const int col = lane & 15, quad = lane >> 4;
    const int cx = col & 7;

    const int b  = (blockIdx.x & 7) >> 1;
    const int th = blockIdx.x & 1;
    const int qt = blockIdx.x >> 3;
    const int q0 = qt * 64;
    const int t_base = th * (S / TSPLIT);
    const int NT = (S / TSPLIT) / 32;

    float temp = fmaxf(__expf(logt[0]), 1e-5f);
    float t2 = temp * temp;
    float t2inv = __builtin_amdgcn_rcpf(t2);

    const unsigned char* xtb = xb8 + (size_t)b * S * D;
    const short* vtb = xt + (size_t)b * D * S;
    const float* sqb = sq + b * S;

    long xq[8];
    {
        const unsigned char* xrow = xtb + (size_t)(q0 + w * 16 + col) * D;
        #pragma unroll
        for (int ks = 0; ks < 8; ks++)
            xq[ks] = *(const long*)(xrow + (((ks * 2 + (quad >> 1)) ^ cx) << 4) + (quad & 1) * 8);
    }
    float sqq[4];
    #pragma unroll
    for (int rr = 0; rr < 4; rr++)
        sqq[rr] = sqb[q0 + w * 16 + quad * 4 + rr];

    f32x4 acc[4][4];
    #pragma unroll
    for (int mi = 0; mi < 4; mi++)
        #pragma unroll
        for (int ni = 0; ni < 4; ni++)
            acc[mi][ni] = (f32x4){0.f, 0.f, 0.f, 0.f};
    float rs[4] = {0.f, 0.f, 0.f, 0.f};

    {   // prologue: async-stage tile 0
        const char* g = (const char*)(xtb + (size_t)t_base * D);
        #pragma unroll
        for (int p = 0; p < 2; p++) {
            int c = p * 256 + tid;
            g2lds16(g + c * 16, &sXt[0][c * 16]);
        }
    }

    for (int i = 0; i < NT; i++) {
        const int t0 = t_base + i * 32;
        const int cur = i & 1;
        __syncthreads();

        if (i + 1 < NT) {
            const char* g = (const char*)(xtb + (size_t)(t0 + 32) * D);
            #pragma unroll
            for (int p = 0; p < 2; p++) {
                int c = p * 256 + tid;
                g2lds16(g + c * 16, &sXt[cur ^ 1][c * 16]);
            }
        }

        bf16x8 vb[4];
        if (i > 0) {
            const int tp = t0 - 32;
            #pragma unroll
            for (int ni = 0; ni < 4; ni++)
                vb[ni] = *(const bf16x8*)(vtb + (size_t)(w * 64 + ni * 16 + col) * S + tp + quad * 8);
        }
        float sqt0 = sqb[t0 + col], sqt1 = sqb[t0 + 16 + col];

        f32x4 p2v[2];
        p2v[0] = (f32x4){0.f, 0.f, 0.f, 0.f};
        p2v[1] = (f32x4){0.f, 0.f, 0.f, 0.f};
        #pragma unroll
        for (int ks = 0; ks < 8; ks++) {
            int co = (((ks * 2 + (quad >> 1)) ^ cx) << 4) + (quad & 1) * 8;
            long b0 = *(const long*)(&sXt[cur][col * 256 + co]);
            long b1 = *(const long*)(&sXt[cur][(col + 16) * 256 + co]);
            p2v[0] = MFMA8(xq[ks], b0, p2v[0]);
            p2v[1] = MFMA8(xq[ks], b1, p2v[1]);
        }

        #pragma unroll
        for (int t_ = 0; t_ < 2; t_++) {
            float sqt = t_ ? sqt1 : sqt0;
            int tg = t0 + t_ * 16 + col;
            #pragma unroll
            for (int rr = 0; rr < 4; rr++) {
                float d2 = fmaxf(sqq[rr] + sqt - 2.f * p2v[t_][rr], 0.f);
                float u = __builtin_amdgcn_rcpf(t2 + d2);   // normalization cancels t2
                if (q0 + w * 16 + quad * 4 + rr == tg) u = t2inv;   // exact diagonal (kv=1)
                rs[rr] += u;
                sK[cur][(w * 16 + quad * 4 + rr) * 36 + t_ * 16 + col] = f2bf(u);
            }
        }

        if (i > 0) {
            #pragma unroll
            for (int mi = 0; mi < 4; mi++) {
                bf16x8 af = *(const bf16x8*)(&sK[cur ^ 1][(mi * 16 + col) * 36 + quad * 8]);
                #pragma unroll
                for (int ni = 0; ni < 4; ni++)
                    acc[mi][ni] = MFMA(af, vb[ni], acc[mi][ni]);
            }
        }
    }

    __syncthreads();
    {   // final PV
        const int tp = t_base + (NT - 1) * 32;
        const int cur = (NT - 1) & 1;
        bf16x8 vb[4];
        #pragma unroll
        for (int ni = 0; ni < 4; ni++)
            vb[ni] = *(const bf16x8*)(vtb + (size_t)(w * 64 + ni * 16 + col) * S + tp + quad * 8);
        #pragma unroll
        for (int mi = 0; mi < 4; mi++) {
            bf16x8 af = *(const bf16x8*)(&sK[cur][(mi * 16 + col) * 36 + quad * 8]);
            #pragma unroll
            for (int ni = 0; ni < 4; ni++)
                acc[mi][ni] = MFMA(af, vb[ni], acc[mi][ni]);
        }
    }

    #pragma unroll
    for (int rr = 0; rr < 4; rr++) {
        float v = rs[rr];
        v += __shfl_xor(v, 1, 64);
        v += __shfl_xor(v, 2, 64);
        v += __shfl_xor(v, 4, 64);
        v += __shfl_xor(v, 8, 64);
        if (col == 0) sRow[w * 16 + quad * 4 + rr] = v;
    }
    __syncthreads();

    if (tid < 64) rws[(size_t)th * NB * S + b * S + q0 + tid] = sRow[tid];
    _Float16* ob = pex + (size_t)th * NB * S * D + (size_t)(b * S + q0) * D;
    #pragma unroll
    for (int mi = 0; mi < 4; mi++)
        #pragma unroll
        for (int rr = 0; rr < 4; rr++)
            #pragma unroll
            for (int ni = 0; ni < 4; ni++)
                ob[(size_t)(mi * 16 + quad * 4 + rr) * D + w * 64 + ni * 16 + col] =
                    (_Float16)acc[mi][ni][rr];
}

// ---------------- post: out = ((Y0+Y1)/(r0+r1)) @ W^T + b ----------------
// 256 threads / 4 waves, 32 s-rows per block, grid 512. Wave w owns d-strip [w*64, +64).
__global__ __launch_bounds__(256) void k_post(const _Float16* __restrict__ pex,
                                              const float* __restrict__ rws,
                                              const short* __restrict__ wb,
                                              const float* __restrict__ bv,
                                              float* __restrict__ out) {
    __shared__ short sY[32 * 264];

    const int tid = threadIdx.x;
    const int w = tid >> 6, lane = tid & 63;
    const int col = lane & 15, quad = lane >> 4;
    const int b = blockIdx.x >> 7, s0 = (blockIdx.x & 127) * 32;

    // W preload (bf16): wf[4][8]
    bf16x8 wf[4][8];
    #pragma unroll
    for (int ni = 0; ni < 4; ni++)
        #pragma unroll
        for (int ks = 0; ks < 8; ks++)
            wf[ni][ks] = *(const bf16x8*)(wb + (size_t)(w * 64 + ni * 16 + col) * D + ks * 32 + quad * 8);

    {   // load partials, normalize, stage bf16
        const int row = tid >> 3, c8 = tid & 7;
        const int gs = b * S + s0 + row;
        float rinv = __builtin_amdgcn_rcpf(fmaxf(rws[gs] + rws[(size_t)NB * S + gs], 1e-8f));
        const _Float16* y0 = pex + (size_t)gs * D + c8 * 32;
        const _Float16* y1 = y0 + (size_t)NB * S * D;
        #pragma unroll
        for (int j = 0; j < 4; j++) {
            h16x8 a = *(const h16x8*)(y0 + j * 8);
            h16x8 c = *(const h16x8*)(y1 + j * 8);
            s16x8 o;
            #pragma unroll
            for (int e = 0; e < 8; e++)
                o[e] = f2bf(((float)a[e] + (float)c[e]) * rinv);
            *(s16x8*)(sY + row * 264 + c8 * 32 + j * 8) = o;
        }
    }
    __syncthreads();

    f32x4 acc[2][4];
    #pragma unroll
    for (int mi = 0; mi < 2; mi++)
        #pragma unroll
        for (int ni = 0; ni < 4; ni++)
            acc[mi][ni] = (f32x4){0.f, 0.f, 0.f, 0.f};

    #pragma unroll
    for (int ks = 0; ks < 8; ks++) {
        bf16x8 a[2];
        #pragma unroll
        for (int mi = 0; mi < 2; mi++)
            a[mi] = *(const bf16x8*)(sY + (mi * 16 + col) * 264 + ks * 32 + quad * 8);
        #pragma unroll
        for (int mi = 0; mi < 2; mi++)
            #pragma unroll
            for (int ni = 0; ni < 4; ni++)
                acc[mi][ni] = MFMA(a[mi], wf[ni][ks], acc[mi][ni]);
    }

    float* ob = out + (size_t)(b * S + s0) * D;
    #pragma unroll
    for (int ni = 0; ni < 4; ni++) {
        int d = w * 64 + ni * 16 + col;
        float bvv = bv[d];
        #pragma unroll
        for (int mi = 0; mi < 2; mi++)
            #pragma unroll
            for (int r = 0; r < 4; r++)
                ob[(size_t)(mi * 16 + quad * 4 + r) * D + d] = acc[mi][ni][r] + bvv;
    }
}

extern "C" void kernel_launch(void* const* d_in, const int* in_sizes, int n_in,
                              void* d_out, int out_size, void* d_ws, size_t ws_size,
                              hipStream_t stream) {
    const float* x    = (const float*)d_in[0];
    const float* Wv   = (const float*)d_in[1];
    const float* bv   = (const float*)d_in[2];
    const float* logt = (const float*)d_in[3];
    float* out = (float*)d_out;

    char* ws = (char*)d_ws;
    unsigned char* xb8 = (unsigned char*)ws;          // fp8 x (swizzled) [B][S][D]   4 MB
    short* xt  = (short*)(ws + 4194304);              // bf16 x^T [B][D][S]           8 MB
    short* wb  = (short*)(ws + 12582912);             // bf16 W [D][D]                128 KB
    float* sq  = (float*)(ws + 12713984);             // ||x||^2 [B][S]               64 KB
    float* rws = (float*)(ws + 12779520);             // rowsums [2][B][S]            128 KB
    _Float16* pex = (_Float16*)(ws + 12910592);       // fp16 Y partials [2][B][S][D] 16.78 MB

    k_prep<<<528, 256, 0, stream>>>(x, Wv, xb8, xt, wb, sq);
    k_attn<2><<<NB * (S / 64) * 2, 256, 0, stream>>>(xb8, xt, sq, logt, pex, rws);
    k_post<<<NB * (S / 32), 256, 0, stream>>>(pex, rws, wb, bv, out);
}